// Round 5
// baseline (33.795 us; speedup 1.0000x reference)
//
#include <hip/hip_runtime.h>

// TV-like sum over interior 62x62 of each 64x64 image, edge-pair formulation:
//   vertical edge (i,i+1), col c in [1,62]: weight = [i in 1..62] + [i+1 in 1..62]
//   horizontal edge (c,c+1), row r in [1,62]: weight = [c in 1..62] + [c+1 in 1..62]
// Every element loaded once (+1 extra 256B row per image for the cross-wave
// half boundary). 128 threads/image: half h = rows 32h..32h+31; within a wave,
// lane-group g=w>>4 owns rows 32h+8g..+7, lane l=w&15 owns cols 4l..4l+3.
// v[8] float4 = 32 data VGPRs -> 64-VGPR cap -> 32 waves/CU occupancy.

__global__ __launch_bounds__(1024, 8) void tv_fused(const float* __restrict__ fai,
                                                    float* __restrict__ out) {
    const int tid  = threadIdx.x;
    const int w    = tid & 63;
    const int img  = blockIdx.x * 8 + (tid >> 7);   // 8 images per block
    const int half = (tid >> 6) & 1;                // 0: rows 0-31, 1: rows 32-63
    const int l    = w & 15;                        // cols 4l..4l+3
    const int g    = w >> 4;                        // 8-row group within half
    const int r0   = half * 32 + g * 8;

    const float4* src4 = (const float4*)(fai + (size_t)img * 4096);
    const float4* base = src4 + r0 * 16 + l;        // imm offsets rr*256B

    // 8 back-to-back global_load_dwordx4.
    float4 v[8];
#pragma unroll
    for (int rr = 0; rr < 8; ++rr) v[rr] = base[rr * 16];

    // Boundary row r0+8: for g<3 it's lane (w+16)'s v[0] (same wave).
    float4 b;
    b.x = __shfl_down(v[0].x, 16, 64);
    b.y = __shfl_down(v[0].y, 16, 64);
    b.z = __shfl_down(v[0].z, 16, 64);
    b.w = __shfl_down(v[0].w, 16, 64);
    // g==3, half==0: row 32 lives in the other wave -> exec-masked reload.
    if (g == 3 && half == 0) b = src4[32 * 16 + l];
    // g==3, half==1: row 64 doesn't exist; b stays finite, weight is 0.

    const int c0 = 4 * l, c2 = c0 + 2, c3 = c0 + 3;
    const float vw0 = (c0 >= 1) ? 1.f : 0.f;    // col 0 excluded (l==0)
    const float vw3 = (c3 <= 62) ? 1.f : 0.f;   // col 63 excluded (l==15)
    const float hw0 = (c0 == 0) ? 1.f : 2.f;    // edge (c0,c0+1)
    const float hw2 = (c2 == 62) ? 1.f : 2.f;   // edge (c2,c2+1)
    const float hw3 = (c3 <= 62) ? 2.f : 0.f;   // edge (c3,c3+1): gone at l==15

    float acc = 0.f;
#pragma unroll
    for (int rr = 0; rr < 8; ++rr) {
        const float4 cur = v[rr];
        const int hr = r0 + rr;
        // Horizontal edges on row hr (interior rows only).
        const float hrow = (hr >= 1 && hr <= 62) ? 1.f : 0.f;
        const float nx = __shfl_down(cur.x, 1, 64);     // next lane's col c3+1
        acc += hrow * (hw0 * fabsf(cur.x - cur.y) + 2.f * fabsf(cur.y - cur.z)
                     + hw2 * fabsf(cur.z - cur.w) + hw3 * fabsf(cur.w - nx));
        // Vertical edge (hr, hr+1).
        const float4 nxt = (rr < 7) ? v[rr + 1] : b;
        const float wv = (hr == 0 || hr == 62) ? 1.f : (hr < 63 ? 2.f : 0.f);
        acc += wv * (vw0 * fabsf(cur.x - nxt.x) + fabsf(cur.y - nxt.y)
                   + fabsf(cur.z - nxt.z) + vw3 * fabsf(cur.w - nxt.w));
    }

    // Wave(64) shuffle reduction.
#pragma unroll
    for (int off = 32; off > 0; off >>= 1) acc += __shfl_down(acc, off, 64);

    // Cross-wave reduction (16 waves), one atomic per block.
    __shared__ float wsum[16];
    if (w == 0) wsum[tid >> 6] = acc;
    __syncthreads();
    if (tid == 0) {
        float s = 0.f;
#pragma unroll
        for (int i = 0; i < 16; ++i) s += wsum[i];
        atomicAdd(out, s);
    }
}

extern "C" void kernel_launch(void* const* d_in, const int* in_sizes, int n_in,
                              void* d_out, int out_size, void* d_ws, size_t ws_size,
                              hipStream_t stream) {
    const float* fai = (const float*)d_in[0];
    float* out = (float*)d_out;

    // d_out is poisoned once and not re-poisoned between replays; we
    // accumulate with atomics, so zero it every call (capture-safe).
    hipMemsetAsync(out, 0, sizeof(float), stream);

    const int n_blocks = 8192 / 8;              // 1024 blocks x 8 images
    tv_fused<<<n_blocks, 1024, 0, stream>>>(fai, out);
}

// Round 6
// 27.393 us; speedup vs baseline: 1.2337x; 1.2337x over previous
//
#include <hip/hip_runtime.h>

// TV-like sum over interior 62x62 of each 64x64 image, edge-pair formulation:
//   vertical edge (i,i+1), col c in [1,62]: weight (i==0||i==62) ? 1 : 2
//   horizontal edge (c,c+1), row r in [1,62]: weight (c==0||c==62) ? 1 : 2
// Every element loaded exactly once. One 64-lane wave processes TWO images,
// all 32 float4 loads issued before compute -> 512B/lane in flight (MLP).
// Layout per image: lane-group l=w&15 owns cols 4l..4l+3, row-group g=w>>4
// owns rows 16g..16g+15; boundary row 16g+16 via __shfl_down(v[0],16).
// Two-stage reduction: stage1 -> d_ws partials (no atomics, no memset),
// stage2 (1 block) overwrites out[0].

__device__ __forceinline__ float tv_image(const float4 v[16], int r0,
                                          float vw0, float vw3,
                                          float hw0, float hw2, float hw3) {
    // Boundary row r0+16 == lane (w+16)'s v[0]; g==3 oob -> own value, weight 0.
    float4 b;
    b.x = __shfl_down(v[0].x, 16, 64);
    b.y = __shfl_down(v[0].y, 16, 64);
    b.z = __shfl_down(v[0].z, 16, 64);
    b.w = __shfl_down(v[0].w, 16, 64);

    float acc = 0.f;
#pragma unroll
    for (int rr = 0; rr < 16; ++rr) {
        const float4 cur = v[rr];
        const int hr = r0 + rr;
        const float hrow = (hr >= 1 && hr <= 62) ? 1.f : 0.f;
        const float nx = __shfl_down(cur.x, 1, 64);     // next lane's col c3+1
        acc += hrow * (hw0 * fabsf(cur.x - cur.y) + 2.f * fabsf(cur.y - cur.z)
                     + hw2 * fabsf(cur.z - cur.w) + hw3 * fabsf(cur.w - nx));
        const float4 nxt = (rr < 15) ? v[rr + 1] : b;
        const float wv = (hr == 0 || hr == 62) ? 1.f : (hr < 63 ? 2.f : 0.f);
        acc += wv * (vw0 * fabsf(cur.x - nxt.x) + fabsf(cur.y - nxt.y)
                   + fabsf(cur.z - nxt.z) + vw3 * fabsf(cur.w - nxt.w));
    }
    return acc;
}

__global__ __launch_bounds__(256, 3) void tv_stage1(const float* __restrict__ fai,
                                                    float* __restrict__ partial) {
    const int tid  = threadIdx.x;
    const int w    = tid & 63;
    const int wave = blockIdx.x * 4 + (tid >> 6);    // 4 waves/block
    const int l    = w & 15;                         // cols 4l..4l+3
    const int r0   = (w >> 4) * 16;                  // rows 16g..16g+15

    // Two consecutive images per wave (contiguous 32KB -> DRAM locality).
    const float4* a4 = (const float4*)(fai + (size_t)(2 * wave) * 4096) + r0 * 16 + l;
    const float4* b4 = a4 + 1024;                    // next image

    // Issue ALL 32 loads back-to-back before any use.
    float4 vA[16], vB[16];
#pragma unroll
    for (int rr = 0; rr < 16; ++rr) vA[rr] = a4[rr * 16];
#pragma unroll
    for (int rr = 0; rr < 16; ++rr) vB[rr] = b4[rr * 16];

    const int c0 = 4 * l, c2 = c0 + 2, c3 = c0 + 3;
    const float vw0 = (c0 >= 1) ? 1.f : 0.f;    // col 0 excluded (l==0)
    const float vw3 = (c3 <= 62) ? 1.f : 0.f;   // col 63 excluded (l==15)
    const float hw0 = (c0 == 0) ? 1.f : 2.f;
    const float hw2 = (c2 == 62) ? 1.f : 2.f;
    const float hw3 = (c3 <= 62) ? 2.f : 0.f;   // absent at l==15

    float acc = tv_image(vA, r0, vw0, vw3, hw0, hw2, hw3)
              + tv_image(vB, r0, vw0, vw3, hw0, hw2, hw3);

    // Wave(64) shuffle reduction.
#pragma unroll
    for (int off = 32; off > 0; off >>= 1) acc += __shfl_down(acc, off, 64);

    __shared__ float wsum[4];
    if (w == 0) wsum[tid >> 6] = acc;
    __syncthreads();
    if (tid == 0)
        partial[blockIdx.x] = (wsum[0] + wsum[1]) + (wsum[2] + wsum[3]);
}

__global__ __launch_bounds__(256) void tv_stage2(const float* __restrict__ partial,
                                                 float* __restrict__ out) {
    // 1024 partials = 256 x float4.
    const float4 p = ((const float4*)partial)[threadIdx.x];
    float acc = (p.x + p.y) + (p.z + p.w);
#pragma unroll
    for (int off = 32; off > 0; off >>= 1) acc += __shfl_down(acc, off, 64);
    __shared__ float wsum[4];
    if ((threadIdx.x & 63) == 0) wsum[threadIdx.x >> 6] = acc;
    __syncthreads();
    if (threadIdx.x == 0)
        out[0] = (wsum[0] + wsum[1]) + (wsum[2] + wsum[3]);  // pure overwrite
}

extern "C" void kernel_launch(void* const* d_in, const int* in_sizes, int n_in,
                              void* d_out, int out_size, void* d_ws, size_t ws_size,
                              hipStream_t stream) {
    const float* fai = (const float*)d_in[0];
    float* out = (float*)d_out;
    float* partial = (float*)d_ws;              // 1024 floats, fully overwritten

    const int n_blocks = 8192 / 8;              // 2 imgs/wave x 4 waves/block
    tv_stage1<<<n_blocks, 256, 0, stream>>>(fai, partial);
    tv_stage2<<<1, 256, 0, stream>>>(partial, out);
}